// Round 9
// baseline (245.239 us; speedup 1.0000x reference)
//
#include <hip/hip_runtime.h>

// SAGE 2-layer GraphSAGE (mean aggr) on MI355X.
// Pipeline: memset -> setup(bin+convert+prep) -> fill2 -> [agg -> gemm] x2.
//           (7 dispatches)
// R1: hierarchical scan (single-block scan was 108us on 1 CU).
// R2: bucket-local CSR build (random scatter had 16x write amplification).
// R3: LDS-free GEMM w/ pre-formatted bf16 B-frags (bank conflicts + 2 blk/CU).
// R4-R6: fused setup (bin blocks FIRST in grid), fill2 block=1024.
// R7: REGRESSION: agg fused into gemm block cut agg waves 50000->3128 (79us).
//     agg must keep 1 wave/node.
// R8: best=230.6us. R6 vs R8 proved gemm is occupancy-limited (32-row tile
//     with half the waves lost 5us/layer vs 16-row).
// R9: NBIN 784->1568 (bin latency-bound, 6 blk/CU); gemm tile 16x64 per wave
//     (2x waves = 24.4/CU, same B traffic, 2x latency hiding).

typedef __attribute__((ext_vector_type(8))) short short8;
typedef __attribute__((ext_vector_type(4))) float f32x4;

#define DEV __device__ __forceinline__

DEV unsigned short f2b(float f) {
  unsigned u = __builtin_bit_cast(unsigned, f);
  u += 0x7fffu + ((u >> 16) & 1u);   // round-to-nearest-even
  return (unsigned short)(u >> 16);
}
DEV float b2f(unsigned short h) {
  unsigned u = ((unsigned)h) << 16;
  return __builtin_bit_cast(float, u);
}

constexpr int N_NODES = 50000;
constexpr int N_EDGES = 800000;
constexpr int D = 128;
constexpr int NBUCK = (N_NODES + 255) / 256;          // 196 buckets of 256 nodes
constexpr int BCAP = 5120;                            // mean 4096, +16 sigma
constexpr int NBIN = 1568;                            // bin blocks (6/CU)
constexpr int EPB = (N_EDGES + NBIN - 1) / NBIN;      // 511 edges per bin block
constexpr int NCONV = (N_NODES * D / 4) / 256;        // 6250 convert blocks
constexpr int NPREP = (2 * 32 * 128) / 256;           // 32 prep blocks

// ---------------- fused setup: bin | convert | prep_weights ----------------
// bin blocks FIRST: latency-bound long pole; convert streams around them.
__global__ __launch_bounds__(256) void setup_kernel(
    const float* __restrict__ x, unsigned short* __restrict__ xb,
    const float* __restrict__ Wl0, const float* __restrict__ Wr0,
    const float* __restrict__ Wl1, const float* __restrict__ Wr1,
    unsigned short* __restrict__ Bf,
    const int* __restrict__ src, const int* __restrict__ dst,
    int* __restrict__ g_bcnt, unsigned* __restrict__ staging) {
  __shared__ int cnt[NBUCK];
  __shared__ int cur[NBUCK];
  int bid = blockIdx.x;
  int t = threadIdx.x;

  if (bid < NBIN) {
    // bin: bucket edges, packed (dloc<<16)|src (src < 2^16)
    for (int i = t; i < NBUCK; i += 256) cnt[i] = 0;
    __syncthreads();
    int beg = bid * EPB;
    int end = min(beg + EPB, N_EDGES);
    for (int e = beg + t; e < end; e += 256) {
      atomicAdd(&cnt[dst[e] >> 8], 1);
    }
    __syncthreads();
    for (int i = t; i < NBUCK; i += 256) {
      cur[i] = atomicAdd(&g_bcnt[i], cnt[i]);   // contiguous chunk base
    }
    __syncthreads();
    for (int e = beg + t; e < end; e += 256) {
      int d = dst[e];
      int b = d >> 8;
      int p = atomicAdd(&cur[b], 1);
      if (p >= BCAP) p = BCAP - 1;  // paranoia; statistically unreachable
      staging[b * BCAP + p] = ((unsigned)(d & 255) << 16) | (unsigned)src[e];
    }
    return;
  }
  if (bid < NBIN + NCONV) {
    // fp32 -> bf16 feature convert
    int i = (bid - NBIN) * 256 + t;
    f32x4 v = ((const f32x4*)x)[i];
    uint2 o;
    o.x = (unsigned)f2b(v.x) | ((unsigned)f2b(v.y) << 16);
    o.y = (unsigned)f2b(v.z) | ((unsigned)f2b(v.w) << 16);
    ((uint2*)xb)[i] = o;
    return;
  }
  // weights fp32 [out][in] -> bf16 B-fragment order (frag = kchunk*128+n)
  int f = (bid - NBIN - NCONV) * 256 + t;
  int layer = f >> 12;
  int kchunk = (f >> 7) & 31;
  int n = f & 127;
  const float* W;
  if (layer == 0) W = (kchunk < 16) ? Wl0 : Wr0;
  else            W = (kchunk < 16) ? Wl1 : Wr1;
  int k = (kchunk & 15) * 8;
  const f32x4* row = (const f32x4*)(W + n * D + k);
  f32x4 a = row[0], b = row[1];
  uint4 pk;
  pk.x = (unsigned)f2b(a.x) | ((unsigned)f2b(a.y) << 16);
  pk.y = (unsigned)f2b(a.z) | ((unsigned)f2b(a.w) << 16);
  pk.z = (unsigned)f2b(b.x) | ((unsigned)f2b(b.y) << 16);
  pk.w = (unsigned)f2b(b.z) | ((unsigned)f2b(b.w) << 16);
  *(uint4*)(Bf + (size_t)f * 8) = pk;
}

// ---------------- fill2: inline bucket scan + per-bucket CSR fill ----------
__global__ __launch_bounds__(1024) void fill2_kernel(const unsigned* __restrict__ staging,
                                                     const int* __restrict__ g_bcnt,
                                                     int* __restrict__ offs,
                                                     int* __restrict__ csr) {
  __shared__ int cnts[256];
  __shared__ int tmp[256];
  __shared__ int hist[256];
  __shared__ int cur[256];
  __shared__ int sh_n, sh_bb;
  int b = blockIdx.x;
  int t = threadIdx.x;
  if (t < 256) {
    int c = (t < NBUCK) ? g_bcnt[t] : 0;
    cnts[t] = c;
    tmp[t] = c;
    hist[t] = 0;
  }
  __syncthreads();
  if (t < 256) {
    for (int off = 1; off < 256; off <<= 1) {
      int u = (t >= off) ? tmp[t - off] : 0;
      __syncthreads();
      tmp[t] += u;
      __syncthreads();
    }
  } else {
    for (int off = 1; off < 256; off <<= 1) { __syncthreads(); __syncthreads(); }
  }
  if (t == 0) {
    sh_n = cnts[b];
    sh_bb = tmp[b] - cnts[b];   // exclusive prefix for this bucket
  }
  __syncthreads();
  int n = sh_n;
  int bb = sh_bb;
  if (b == 0 && t == 0) offs[N_NODES] = N_EDGES;

  const unsigned* st = staging + b * BCAP;
  for (int e = t; e < n; e += 1024) atomicAdd(&hist[st[e] >> 16], 1);
  __syncthreads();
  if (t < 256) {
    int v = hist[t];
    tmp[t] = v;
    __syncthreads();
    for (int off = 1; off < 256; off <<= 1) {
      int u = (t >= off) ? tmp[t - off] : 0;
      __syncthreads();
      tmp[t] += u;
      __syncthreads();
    }
    int excl = tmp[t] - v;
    int node = b * 256 + t;
    if (node < N_NODES) offs[node] = bb + excl;
    cur[t] = bb + excl;
  } else {
    __syncthreads();
    for (int off = 1; off < 256; off <<= 1) { __syncthreads(); __syncthreads(); }
  }
  __syncthreads();
  for (int e = t; e < n; e += 1024) {
    unsigned pk = st[e];
    int p = atomicAdd(&cur[pk >> 16], 1);
    csr[p] = (int)(pk & 0xffffu);
  }
}

// ---------------- mean aggregation: one wave per node ----------------
// 50000 waves; each lane owns one dword (2 cols); fp32 accumulate.
__global__ void agg_kernel(const unsigned short* __restrict__ feat,
                           const int* __restrict__ csr_src,
                           const int* __restrict__ offs,
                           unsigned short* __restrict__ out) {
  int w = (int)((blockIdx.x * blockDim.x + threadIdx.x) >> 6);
  int lane = threadIdx.x & 63;
  if (w >= N_NODES) return;
  int s = offs[w], e = offs[w + 1];
  const unsigned* f = (const unsigned*)feat;  // 64 dwords per row
  float ax = 0.f, ay = 0.f;
  int k = s;
  for (; k + 4 <= e; k += 4) {
    int s0 = csr_src[k], s1 = csr_src[k + 1], s2 = csr_src[k + 2], s3 = csr_src[k + 3];
    unsigned u0 = f[s0 * 64 + lane];
    unsigned u1 = f[s1 * 64 + lane];
    unsigned u2 = f[s2 * 64 + lane];
    unsigned u3 = f[s3 * 64 + lane];
    ax += b2f((unsigned short)u0) + b2f((unsigned short)u1) +
          b2f((unsigned short)u2) + b2f((unsigned short)u3);
    ay += b2f((unsigned short)(u0 >> 16)) + b2f((unsigned short)(u1 >> 16)) +
          b2f((unsigned short)(u2 >> 16)) + b2f((unsigned short)(u3 >> 16));
  }
  for (; k < e; ++k) {
    unsigned u = f[csr_src[k] * 64 + lane];
    ax += b2f((unsigned short)u);
    ay += b2f((unsigned short)(u >> 16));
  }
  float inv = 1.0f / (float)max(e - s, 1);
  unsigned o = (unsigned)f2b(ax * inv) | ((unsigned)f2b(ay * inv) << 16);
  ((unsigned*)out)[w * 64 + lane] = o;
}

// ---------------- LDS-free fused SAGE GEMM, 16 rows x 64 cols per wave -----
// out[i,:] = Aagg[i,:] @ Wl^T + Afeat[i,:] @ Wr^T + bias  (+optional ReLU)
// Block = 4 waves covers 32 rows x 128 cols: wave = (rh<<1)|nh,
// rh = rows 0-15/16-31, nh = cols 0-63/64-127. 6252 waves = 24.4/CU.
__global__ __launch_bounds__(256) void gemm_kernel(
    const unsigned short* __restrict__ Aagg,   // [N][128] bf16
    const unsigned short* __restrict__ Afeat,  // [N][128] bf16
    const unsigned short* __restrict__ Bf,     // frag-ordered weights, this layer
    const float* __restrict__ bias,            // [128]
    float* __restrict__ out_f32,               // used if relu_bf16 == 0
    unsigned short* __restrict__ out_bf16,     // used if relu_bf16 == 1
    int relu_bf16) {
  int wave = threadIdx.x >> 6;
  int lane = threadIdx.x & 63;
  int ml = lane & 15;     // A: m / B: n / C: col
  int quad = lane >> 4;   // A,B: k-sub / C: row group
  int rh = wave >> 1;     // row half of the block's 32 rows
  int nh = wave & 1;      // col half (64 cols)
  int node0 = blockIdx.x * 32 + rh * 16;

  int arow = node0 + ml;
  if (arow >= N_NODES) arow = N_NODES - 1;  // clamp; stores guarded below

  f32x4 acc[4];
#pragma unroll
  for (int t = 0; t < 4; ++t) acc[t] = (f32x4){0.f, 0.f, 0.f, 0.f};

  const short8* bf8 = (const short8*)Bf;  // frag idx = kchunk*128 + n
#pragma unroll
  for (int mat = 0; mat < 2; ++mat) {
    const unsigned short* A = mat ? Afeat : Aagg;
    const short8* arow8 = (const short8*)(A + (size_t)arow * D);  // 16 frags/row
    int kbase = mat * 16;
#pragma unroll
    for (int kc = 0; kc < 4; ++kc) {
      short8 af = arow8[kc * 4 + quad];          // A[m][kc*32 + quad*8 ..+8]
      int kchunk = kbase + kc * 4 + quad;
      const short8* brow = bf8 + kchunk * 128 + nh * 64;
#pragma unroll
      for (int nt = 0; nt < 4; ++nt) {
        short8 bfr = brow[nt * 16 + ml];         // W[n][k..k+8]
        acc[nt] = __builtin_amdgcn_mfma_f32_16x16x32_bf16(af, bfr, acc[nt], 0, 0, 0);
      }
    }
  }

  // Epilogue: C/D layout col = lane&15, row = quad*4 + reg.
#pragma unroll
  for (int nt = 0; nt < 4; ++nt) {
    int col = nh * 64 + nt * 16 + ml;
    float bv = bias[col];
#pragma unroll
    for (int r = 0; r < 4; ++r) {
      int node = node0 + quad * 4 + r;
      if (node >= N_NODES) continue;
      float v = acc[nt][r] + bv;
      if (relu_bf16) {
        v = v > 0.f ? v : 0.f;
        out_bf16[(size_t)node * D + col] = f2b(v);
      } else {
        out_f32[(size_t)node * D + col] = v;
      }
    }
  }
}

extern "C" void kernel_launch(void* const* d_in, const int* in_sizes, int n_in,
                              void* d_out, int out_size, void* d_ws, size_t ws_size,
                              hipStream_t stream) {
  const float* x   = (const float*)d_in[0];
  const int*   ei  = (const int*)d_in[1];   // [2][E] int32
  const float* Wl0 = (const float*)d_in[2];
  const float* bl0 = (const float*)d_in[3];
  const float* Wr0 = (const float*)d_in[4];
  const float* Wl1 = (const float*)d_in[5];
  const float* bl1 = (const float*)d_in[6];
  const float* Wr1 = (const float*)d_in[7];
  float* out = (float*)d_out;

  char* ws = (char*)d_ws;
  size_t o = 0;
  auto carve = [&](size_t bytes) {
    char* p = ws + o;
    o += bytes;
    o = (o + 255) & ~(size_t)255;
    return p;
  };
  int* offs       = (int*)carve((size_t)(N_NODES + 1) * 4);
  int* csr        = (int*)carve((size_t)N_EDGES * 4);
  int* g_bcnt     = (int*)carve((size_t)NBUCK * 4);
  unsigned* staging = (unsigned*)carve((size_t)NBUCK * BCAP * 4);
  unsigned short* Bf   = (unsigned short*)carve((size_t)2 * 32 * 128 * 8 * 2);
  unsigned short* xb   = (unsigned short*)carve((size_t)N_NODES * D * 2);
  unsigned short* aggb = (unsigned short*)carve((size_t)N_NODES * D * 2);
  unsigned short* hb   = (unsigned short*)carve((size_t)N_NODES * D * 2);

  const int* srcp = ei;
  const int* dstp = ei + N_EDGES;

  hipMemsetAsync(g_bcnt, 0, (size_t)NBUCK * 4, stream);
  setup_kernel<<<NBIN + NCONV + NPREP, 256, 0, stream>>>(
      x, xb, Wl0, Wr0, Wl1, Wr1, Bf, srcp, dstp, g_bcnt, staging);
  fill2_kernel<<<NBUCK, 1024, 0, stream>>>(staging, g_bcnt, offs, csr);

  const int GEMM_BLOCKS = (N_NODES + 31) / 32;  // 1563
  // Layer 0: agg(x) ; h = relu([agg|x] @ [Wl0|Wr0]^T + b0) -> bf16
  agg_kernel<<<(N_NODES + 3) / 4, 256, 0, stream>>>(xb, csr, offs, aggb);
  gemm_kernel<<<GEMM_BLOCKS, 256, 0, stream>>>(aggb, xb, Bf, bl0, nullptr, hb, 1);
  // Layer 1: agg(h) ; out = [agg|h] @ [Wl1|Wr1]^T + b1 -> fp32
  agg_kernel<<<(N_NODES + 3) / 4, 256, 0, stream>>>(hb, csr, offs, aggb);
  gemm_kernel<<<GEMM_BLOCKS, 256, 0, stream>>>(aggb, hb, Bf + 32 * 128 * 8, bl1,
                                               out, nullptr, 0);
}

// Round 10
// 230.426 us; speedup vs baseline: 1.0643x; 1.0643x over previous
//
#include <hip/hip_runtime.h>

// SAGE 2-layer GraphSAGE (mean aggr) on MI355X.
// Pipeline: memset -> setup(bin+convert+prep) -> fill2 -> [agg -> gemm] x2.
//           (7 dispatches)  == R8 configuration, the measured best (230.6us) ==
// R1: hierarchical scan (single-block scan was 108us on 1 CU).
// R2: bucket-local CSR build (random scatter had 16x write amplification).
// R3: LDS-free GEMM w/ pre-formatted bf16 B-frags (bank conflicts + 2 blk/CU).
// R4-R6: fused setup (bin blocks FIRST in grid), fill2 block=1024.
// R7: REGRESSION: agg fused into gemm block cut agg waves 50000->3128 (79us).
//     agg must keep 1 wave/node.
// R8: best=230.6us.
// R9: REGRESSION (245us): NBIN 1568 fragmented staging chunks to ~10B ->
//     partial-line writes (WRITE_SIZE 16.7->24MB) + 2x g_bcnt atomics;
//     gemm 16x64 tile (6252 waves) lost ~4-5us/layer vs 16x128 (3128 waves).
//     Measured optima: NBIN=784; gemm 16 rows x 128 cols per wave.

typedef __attribute__((ext_vector_type(8))) short short8;
typedef __attribute__((ext_vector_type(4))) float f32x4;

#define DEV __device__ __forceinline__

DEV unsigned short f2b(float f) {
  unsigned u = __builtin_bit_cast(unsigned, f);
  u += 0x7fffu + ((u >> 16) & 1u);   // round-to-nearest-even
  return (unsigned short)(u >> 16);
}
DEV float b2f(unsigned short h) {
  unsigned u = ((unsigned)h) << 16;
  return __builtin_bit_cast(float, u);
}

constexpr int N_NODES = 50000;
constexpr int N_EDGES = 800000;
constexpr int D = 128;
constexpr int NBUCK = (N_NODES + 255) / 256;          // 196 buckets of 256 nodes
constexpr int BCAP = 5120;                            // mean 4096, +16 sigma
constexpr int NBIN = 784;                             // bin blocks (3/CU) - measured optimum
constexpr int EPB = (N_EDGES + NBIN - 1) / NBIN;      // 1021 edges per bin block
constexpr int NCONV = (N_NODES * D / 4) / 256;        // 6250 convert blocks
constexpr int NPREP = (2 * 32 * 128) / 256;           // 32 prep blocks

// ---------------- fused setup: bin | convert | prep_weights ----------------
// bin blocks FIRST: latency-bound long pole; convert streams around them.
__global__ __launch_bounds__(256) void setup_kernel(
    const float* __restrict__ x, unsigned short* __restrict__ xb,
    const float* __restrict__ Wl0, const float* __restrict__ Wr0,
    const float* __restrict__ Wl1, const float* __restrict__ Wr1,
    unsigned short* __restrict__ Bf,
    const int* __restrict__ src, const int* __restrict__ dst,
    int* __restrict__ g_bcnt, unsigned* __restrict__ staging) {
  __shared__ int cnt[NBUCK];
  __shared__ int cur[NBUCK];
  int bid = blockIdx.x;
  int t = threadIdx.x;

  if (bid < NBIN) {
    // bin: bucket edges, packed (dloc<<16)|src (src < 2^16)
    for (int i = t; i < NBUCK; i += 256) cnt[i] = 0;
    __syncthreads();
    int beg = bid * EPB;
    int end = min(beg + EPB, N_EDGES);
    for (int e = beg + t; e < end; e += 256) {
      atomicAdd(&cnt[dst[e] >> 8], 1);
    }
    __syncthreads();
    for (int i = t; i < NBUCK; i += 256) {
      cur[i] = atomicAdd(&g_bcnt[i], cnt[i]);   // contiguous chunk base
    }
    __syncthreads();
    for (int e = beg + t; e < end; e += 256) {
      int d = dst[e];
      int b = d >> 8;
      int p = atomicAdd(&cur[b], 1);
      if (p >= BCAP) p = BCAP - 1;  // paranoia; statistically unreachable
      staging[b * BCAP + p] = ((unsigned)(d & 255) << 16) | (unsigned)src[e];
    }
    return;
  }
  if (bid < NBIN + NCONV) {
    // fp32 -> bf16 feature convert
    int i = (bid - NBIN) * 256 + t;
    f32x4 v = ((const f32x4*)x)[i];
    uint2 o;
    o.x = (unsigned)f2b(v.x) | ((unsigned)f2b(v.y) << 16);
    o.y = (unsigned)f2b(v.z) | ((unsigned)f2b(v.w) << 16);
    ((uint2*)xb)[i] = o;
    return;
  }
  // weights fp32 [out][in] -> bf16 B-fragment order (frag = kchunk*128+n)
  int f = (bid - NBIN - NCONV) * 256 + t;
  int layer = f >> 12;
  int kchunk = (f >> 7) & 31;
  int n = f & 127;
  const float* W;
  if (layer == 0) W = (kchunk < 16) ? Wl0 : Wr0;
  else            W = (kchunk < 16) ? Wl1 : Wr1;
  int k = (kchunk & 15) * 8;
  const f32x4* row = (const f32x4*)(W + n * D + k);
  f32x4 a = row[0], b = row[1];
  uint4 pk;
  pk.x = (unsigned)f2b(a.x) | ((unsigned)f2b(a.y) << 16);
  pk.y = (unsigned)f2b(a.z) | ((unsigned)f2b(a.w) << 16);
  pk.z = (unsigned)f2b(b.x) | ((unsigned)f2b(b.y) << 16);
  pk.w = (unsigned)f2b(b.z) | ((unsigned)f2b(b.w) << 16);
  *(uint4*)(Bf + (size_t)f * 8) = pk;
}

// ---------------- fill2: inline bucket scan + per-bucket CSR fill ----------
__global__ __launch_bounds__(1024) void fill2_kernel(const unsigned* __restrict__ staging,
                                                     const int* __restrict__ g_bcnt,
                                                     int* __restrict__ offs,
                                                     int* __restrict__ csr) {
  __shared__ int cnts[256];
  __shared__ int tmp[256];
  __shared__ int hist[256];
  __shared__ int cur[256];
  __shared__ int sh_n, sh_bb;
  int b = blockIdx.x;
  int t = threadIdx.x;
  if (t < 256) {
    int c = (t < NBUCK) ? g_bcnt[t] : 0;
    cnts[t] = c;
    tmp[t] = c;
    hist[t] = 0;
  }
  __syncthreads();
  if (t < 256) {
    for (int off = 1; off < 256; off <<= 1) {
      int u = (t >= off) ? tmp[t - off] : 0;
      __syncthreads();
      tmp[t] += u;
      __syncthreads();
    }
  } else {
    for (int off = 1; off < 256; off <<= 1) { __syncthreads(); __syncthreads(); }
  }
  if (t == 0) {
    sh_n = cnts[b];
    sh_bb = tmp[b] - cnts[b];   // exclusive prefix for this bucket
  }
  __syncthreads();
  int n = sh_n;
  int bb = sh_bb;
  if (b == 0 && t == 0) offs[N_NODES] = N_EDGES;

  const unsigned* st = staging + b * BCAP;
  for (int e = t; e < n; e += 1024) atomicAdd(&hist[st[e] >> 16], 1);
  __syncthreads();
  if (t < 256) {
    int v = hist[t];
    tmp[t] = v;
    __syncthreads();
    for (int off = 1; off < 256; off <<= 1) {
      int u = (t >= off) ? tmp[t - off] : 0;
      __syncthreads();
      tmp[t] += u;
      __syncthreads();
    }
    int excl = tmp[t] - v;
    int node = b * 256 + t;
    if (node < N_NODES) offs[node] = bb + excl;
    cur[t] = bb + excl;
  } else {
    __syncthreads();
    for (int off = 1; off < 256; off <<= 1) { __syncthreads(); __syncthreads(); }
  }
  __syncthreads();
  for (int e = t; e < n; e += 1024) {
    unsigned pk = st[e];
    int p = atomicAdd(&cur[pk >> 16], 1);
    csr[p] = (int)(pk & 0xffffu);
  }
}

// ---------------- mean aggregation: one wave per node ----------------
// 50000 waves; each lane owns one dword (2 cols); fp32 accumulate.
__global__ void agg_kernel(const unsigned short* __restrict__ feat,
                           const int* __restrict__ csr_src,
                           const int* __restrict__ offs,
                           unsigned short* __restrict__ out) {
  int w = (int)((blockIdx.x * blockDim.x + threadIdx.x) >> 6);
  int lane = threadIdx.x & 63;
  if (w >= N_NODES) return;
  int s = offs[w], e = offs[w + 1];
  const unsigned* f = (const unsigned*)feat;  // 64 dwords per row
  float ax = 0.f, ay = 0.f;
  int k = s;
  for (; k + 4 <= e; k += 4) {
    int s0 = csr_src[k], s1 = csr_src[k + 1], s2 = csr_src[k + 2], s3 = csr_src[k + 3];
    unsigned u0 = f[s0 * 64 + lane];
    unsigned u1 = f[s1 * 64 + lane];
    unsigned u2 = f[s2 * 64 + lane];
    unsigned u3 = f[s3 * 64 + lane];
    ax += b2f((unsigned short)u0) + b2f((unsigned short)u1) +
          b2f((unsigned short)u2) + b2f((unsigned short)u3);
    ay += b2f((unsigned short)(u0 >> 16)) + b2f((unsigned short)(u1 >> 16)) +
          b2f((unsigned short)(u2 >> 16)) + b2f((unsigned short)(u3 >> 16));
  }
  for (; k < e; ++k) {
    unsigned u = f[csr_src[k] * 64 + lane];
    ax += b2f((unsigned short)u);
    ay += b2f((unsigned short)(u >> 16));
  }
  float inv = 1.0f / (float)max(e - s, 1);
  unsigned o = (unsigned)f2b(ax * inv) | ((unsigned)f2b(ay * inv) << 16);
  ((unsigned*)out)[w * 64 + lane] = o;
}

// ---------------- LDS-free fused SAGE GEMM, 16 nodes/wave ----------------
// out[i,:] = Aagg[i,:] @ Wl^T + Afeat[i,:] @ Wr^T + bias  (+optional ReLU)
// 782 blocks x 4 waves = 3128 waves (measured optimum vs 1564 / 6252).
__global__ __launch_bounds__(256) void gemm_kernel(
    const unsigned short* __restrict__ Aagg,   // [N][128] bf16
    const unsigned short* __restrict__ Afeat,  // [N][128] bf16
    const unsigned short* __restrict__ Bf,     // frag-ordered weights, this layer
    const float* __restrict__ bias,            // [128]
    float* __restrict__ out_f32,               // used if relu_bf16 == 0
    unsigned short* __restrict__ out_bf16,     // used if relu_bf16 == 1
    int relu_bf16) {
  int wave = threadIdx.x >> 6;
  int lane = threadIdx.x & 63;
  int ml = lane & 15;     // A: m / B: n / C: col
  int quad = lane >> 4;   // A,B: k-sub / C: row group
  int node0 = blockIdx.x * 64 + wave * 16;

  int arow = node0 + ml;
  if (arow >= N_NODES) arow = N_NODES - 1;  // clamp; stores guarded below

  f32x4 acc[8];
#pragma unroll
  for (int t = 0; t < 8; ++t) acc[t] = (f32x4){0.f, 0.f, 0.f, 0.f};

  const short8* bf8 = (const short8*)Bf;  // frag idx = kchunk*128 + n
#pragma unroll
  for (int mat = 0; mat < 2; ++mat) {
    const unsigned short* A = mat ? Afeat : Aagg;
    const short8* arow8 = (const short8*)(A + (size_t)arow * D);  // 16 frags/row
    int kbase = mat * 16;
#pragma unroll
    for (int kc = 0; kc < 4; ++kc) {
      short8 af = arow8[kc * 4 + quad];          // A[m][kc*32 + quad*8 ..+8]
      int kchunk = kbase + kc * 4 + quad;
      const short8* brow = bf8 + kchunk * 128;
#pragma unroll
      for (int nt = 0; nt < 8; ++nt) {
        short8 bfr = brow[nt * 16 + ml];         // W[n][k..k+8]
        acc[nt] = __builtin_amdgcn_mfma_f32_16x16x32_bf16(af, bfr, acc[nt], 0, 0, 0);
      }
    }
  }

  // Epilogue: C/D layout col = lane&15, row = quad*4 + reg.
#pragma unroll
  for (int nt = 0; nt < 8; ++nt) {
    int col = nt * 16 + ml;
    float bv = bias[col];
#pragma unroll
    for (int r = 0; r < 4; ++r) {
      int node = node0 + quad * 4 + r;
      if (node >= N_NODES) continue;
      float v = acc[nt][r] + bv;
      if (relu_bf16) {
        v = v > 0.f ? v : 0.f;
        out_bf16[(size_t)node * D + col] = f2b(v);
      } else {
        out_f32[(size_t)node * D + col] = v;
      }
    }
  }
}

extern "C" void kernel_launch(void* const* d_in, const int* in_sizes, int n_in,
                              void* d_out, int out_size, void* d_ws, size_t ws_size,
                              hipStream_t stream) {
  const float* x   = (const float*)d_in[0];
  const int*   ei  = (const int*)d_in[1];   // [2][E] int32
  const float* Wl0 = (const float*)d_in[2];
  const float* bl0 = (const float*)d_in[3];
  const float* Wr0 = (const float*)d_in[4];
  const float* Wl1 = (const float*)d_in[5];
  const float* bl1 = (const float*)d_in[6];
  const float* Wr1 = (const float*)d_in[7];
  float* out = (float*)d_out;

  char* ws = (char*)d_ws;
  size_t o = 0;
  auto carve = [&](size_t bytes) {
    char* p = ws + o;
    o += bytes;
    o = (o + 255) & ~(size_t)255;
    return p;
  };
  int* offs       = (int*)carve((size_t)(N_NODES + 1) * 4);
  int* csr        = (int*)carve((size_t)N_EDGES * 4);
  int* g_bcnt     = (int*)carve((size_t)NBUCK * 4);
  unsigned* staging = (unsigned*)carve((size_t)NBUCK * BCAP * 4);
  unsigned short* Bf   = (unsigned short*)carve((size_t)2 * 32 * 128 * 8 * 2);
  unsigned short* xb   = (unsigned short*)carve((size_t)N_NODES * D * 2);
  unsigned short* aggb = (unsigned short*)carve((size_t)N_NODES * D * 2);
  unsigned short* hb   = (unsigned short*)carve((size_t)N_NODES * D * 2);

  const int* srcp = ei;
  const int* dstp = ei + N_EDGES;

  hipMemsetAsync(g_bcnt, 0, (size_t)NBUCK * 4, stream);
  setup_kernel<<<NBIN + NCONV + NPREP, 256, 0, stream>>>(
      x, xb, Wl0, Wr0, Wl1, Wr1, Bf, srcp, dstp, g_bcnt, staging);
  fill2_kernel<<<NBUCK, 1024, 0, stream>>>(staging, g_bcnt, offs, csr);

  const int GEMM_BLOCKS = (N_NODES + 63) / 64;
  // Layer 0: agg(x) ; h = relu([agg|x] @ [Wl0|Wr0]^T + b0) -> bf16
  agg_kernel<<<(N_NODES + 3) / 4, 256, 0, stream>>>(xb, csr, offs, aggb);
  gemm_kernel<<<GEMM_BLOCKS, 256, 0, stream>>>(aggb, xb, Bf, bl0, nullptr, hb, 1);
  // Layer 1: agg(h) ; out = [agg|h] @ [Wl1|Wr1]^T + b1 -> fp32
  agg_kernel<<<(N_NODES + 3) / 4, 256, 0, stream>>>(hb, csr, offs, aggb);
  gemm_kernel<<<GEMM_BLOCKS, 256, 0, stream>>>(aggb, hb, Bf + 32 * 128 * 8, bl1,
                                               out, nullptr, 0);
}